// Round 8
// baseline (155.420 us; speedup 1.0000x reference)
//
#include <hip/hip_runtime.h>
#include <hip/hip_bf16.h>

// Linear layer: out[M,N] = x[M,K] @ W[N,K]^T + b[N], fp32 in/out.
// M=32768, N=512, K=512. bf16 MFMA, fp32 accumulate.
// R5-R9: 2-phase 128x128 reg-staged dbuf -> 53-56 us plateau (= m102's
//   320 TF m97-structure plateau at this FLOP size). R9 falsified the
//   barrier-drain theory. R11 (16 waves/CU) falsified occupancy theory
//   (59 us at 2x waves). All clean rounds: ~2 TB/s, MFMA ~11%.
// R12 (this): the one untried measured lever — global_load_lds staging
//   (m151: +35% vs reg-staging at this tile size; m193: +67% alone).
//   * Stage FP32 tiles straight to LDS via 4 gload_lds/wave/tile (no
//     per-thread load+cvt+ds_write round-trip). cvt f32->bf16 moves to
//     fragment read (same RNE per element -> absmax unchanged).
//   * Counted vmcnt(4) pipeline (T4): prefetch for tile k+1 issued
//     before the wait for tile k; vmcnt never drains in the loop.
//   * Rule-21 swizzle: LDS linear (DMA constraint); bank fix via
//     pre-swizzled global source chunk' = chunk ^ (row&7) (involution),
//     frag reads apply the same XOR -> 2-way (free) on ds_read_b128.
//   * BK=32 f32 tiles: LDS 64 KB -> 2 blocks/CU, 16 waves/CU.
//   Gates: VGPR<=128, WRITE ~66 MB, conflicts ~0, absmax 0.015625.

#define M_DIM 32768
#define N_DIM 512
#define K_DIM 512
#define BM 128
#define BN 128
#define BK 32            // f32 words per K-tile
#define KT (K_DIM / BK)  // 16

typedef __bf16 bf16x8 __attribute__((ext_vector_type(8)));
typedef float floatx4 __attribute__((ext_vector_type(4)));
typedef __attribute__((address_space(3))) void lds_void;
typedef const __attribute__((address_space(1))) void g_void;

__global__ __launch_bounds__(512, 4) void linear_gl(
    const float* __restrict__ A,    // [M, K]
    const float* __restrict__ W,    // [N, K]
    const float* __restrict__ bias, // [N]
    float* __restrict__ C)          // [M, N]
{
    // FP32 tiles, double-buffered: 2 x (16 + 16) KB = 64 KB.
    __shared__ float sA[2][BM * BK];
    __shared__ float sW[2][BN * BK];

    const int t = threadIdx.x;
    // Bijective XCD chunking (1024 % 8 == 0): contiguous wgids per XCD.
    const int wgid = (blockIdx.x & 7) * 128 + (blockIdx.x >> 3);
    const int nT = wgid & 3;
    const int mT = wgid >> 2;
    const int mBlock = mT * BM;
    const int nBlock = nT * BN;

    const int wid = t >> 6;
    const int lane = t & 63;
    const int mW = (wid >> 2) * 64;     // 2 wave-rows of 64
    const int nW = (wid & 3) * 32;      // 4 wave-cols of 32
    const int kh = lane >> 4;
    const int l16 = lane & 15;

    floatx4 acc[4][2];
#pragma unroll
    for (int i = 0; i < 4; ++i)
#pragma unroll
        for (int j = 0; j < 2; ++j)
            acc[i][j] = (floatx4)0.f;

    // ---- staging map (gload_lds): wave wid covers rows [wid*16, +16) of
    // both tiles, as two 8-row instructions. DMA writes LDS linearly at
    // base + lane*16B; lane l covers row lr=l>>3, chunk l&7 of its 8-row
    // group. Pre-swizzled SOURCE: lane fetches global chunk (l&7)^(l>>3),
    // so LDS slot c of row r holds data chunk c^(r&7)  (r&7 == l>>3).
    const int lr = lane >> 3;                       // 0..7
    const int colSw = ((lane & 7) ^ lr) * 4;        // f32 col of fetched 16B
    const float* aStage =
        A + (size_t)(mBlock + wid * 16 + lr) * K_DIM + colSw;
    const float* wStage =
        W + (size_t)(nBlock + wid * 16 + lr) * K_DIM + colSw;

#define STAGE(bufi, kt)                                                       \
    {                                                                         \
        const float* ga = aStage + (kt) * BK;                                 \
        const float* gw = wStage + (kt) * BK;                                 \
        __builtin_amdgcn_global_load_lds(                                     \
            (g_void*)ga, (lds_void*)&sA[(bufi)][(wid * 16) * BK], 16, 0, 0);  \
        __builtin_amdgcn_global_load_lds(                                     \
            (g_void*)(ga + 8 * K_DIM),                                        \
            (lds_void*)&sA[(bufi)][(wid * 16 + 8) * BK], 16, 0, 0);           \
        __builtin_amdgcn_global_load_lds(                                     \
            (g_void*)gw, (lds_void*)&sW[(bufi)][(wid * 16) * BK], 16, 0, 0);  \
        __builtin_amdgcn_global_load_lds(                                     \
            (g_void*)(gw + 8 * K_DIM),                                        \
            (lds_void*)&sW[(bufi)][(wid * 16 + 8) * BK], 16, 0, 0);           \
    }

    // ---- fragment read: need f32 cols kh*8..+7 of row R = data chunks
    // {2kh, 2kh+1}, stored at slots {2kh^(R&7), (2kh+1)^(R&7)}; R&7==l16&7.
    // Bank check: per 16-lane group slots span all 8, 2 lanes each -> free.
    const int s7 = l16 & 7;
    const int oa0 = ((2 * kh) ^ s7) * 4;       // f32 offset of lo 16B
    const int oa1 = ((2 * kh + 1) ^ s7) * 4;   // f32 offset of hi 16B

#define FRAGS(bufi)                                                           \
    bf16x8 aF[4], wF[2];                                                      \
    _Pragma("unroll") for (int i = 0; i < 4; ++i) {                           \
        const int R = (mW + i * 16 + l16) * BK;                               \
        floatx4 lo = *(const floatx4*)&sA[(bufi)][R + oa0];                   \
        floatx4 hi = *(const floatx4*)&sA[(bufi)][R + oa1];                   \
        _Pragma("unroll") for (int j = 0; j < 4; ++j) {                       \
            aF[i][j] = (__bf16)lo[j];                                         \
            aF[i][4 + j] = (__bf16)hi[j];                                     \
        }                                                                     \
    }                                                                         \
    _Pragma("unroll") for (int i2 = 0; i2 < 2; ++i2) {                        \
        const int R = (nW + i2 * 16 + l16) * BK;                              \
        floatx4 lo = *(const floatx4*)&sW[(bufi)][R + oa0];                   \
        floatx4 hi = *(const floatx4*)&sW[(bufi)][R + oa1];                   \
        _Pragma("unroll") for (int j = 0; j < 4; ++j) {                       \
            wF[i2][j] = (__bf16)lo[j];                                        \
            wF[i2][4 + j] = (__bf16)hi[j];                                    \
        }                                                                     \
    }

#define MFMA8()                                                               \
    __builtin_amdgcn_s_setprio(1);                                            \
    _Pragma("unroll") for (int mi = 0; mi < 4; ++mi)                          \
        _Pragma("unroll") for (int ni = 0; ni < 2; ++ni)                      \
            acc[mi][ni] = __builtin_amdgcn_mfma_f32_16x16x32_bf16(            \
                aF[mi], wF[ni], acc[mi][ni], 0, 0, 0);                        \
    __builtin_amdgcn_s_setprio(0);

    // Prologue: tile 0 -> buf 0 (4 loads outstanding per wave).
    STAGE(0, 0);

    int cur = 0;
    for (int kt = 0; kt < KT - 1; ++kt) {
        // bar A: all waves finished reading buf^1 (tile kt-1) -> safe to
        // let the DMA overwrite it. (Frag ds_reads were consumed by the
        // previous MFMA8's compiler-inserted lgkm waits.)
        __builtin_amdgcn_s_barrier();
        STAGE(cur ^ 1, kt + 1);   // issue next tile (8 outstanding)
        // Counted wait: 4 newest (tile kt+1) may fly; tile kt's 4 landed.
        asm volatile("s_waitcnt vmcnt(4)" ::: "memory");
        // bar B: every wave has waited for its own tile-kt contribution,
        // so after this barrier the whole tile is in LDS (m201 pattern).
        __builtin_amdgcn_s_barrier();
        FRAGS(cur);
        MFMA8();
        cur ^= 1;
    }
    // Peeled last tile: nothing left to prefetch; drain and compute.
    asm volatile("s_waitcnt vmcnt(0)" ::: "memory");
    __builtin_amdgcn_s_barrier();
    {
        FRAGS(cur);
        MFMA8();
    }

#undef STAGE
#undef FRAGS
#undef MFMA8

    // Epilogue: D mapping col = lane&15, row = (lane>>4)*4 + reg (verified
    // R5-R11).
#pragma unroll
    for (int ni = 0; ni < 2; ++ni) {
        const int gcol = nBlock + nW + ni * 16 + l16;
        const float bv = bias[gcol];
#pragma unroll
        for (int mi = 0; mi < 4; ++mi) {
            const int rowB = mBlock + mW + mi * 16 + kh * 4;
#pragma unroll
            for (int r = 0; r < 4; ++r)
                C[(size_t)(rowB + r) * N_DIM + gcol] = acc[mi][ni][r] + bv;
        }
    }
}

extern "C" void kernel_launch(void* const* d_in, const int* in_sizes, int n_in,
                              void* d_out, int out_size, void* d_ws, size_t ws_size,
                              hipStream_t stream) {
    const float* x = (const float*)d_in[0];
    const float* w = (const float*)d_in[1];
    const float* b = (const float*)d_in[2];
    float* out = (float*)d_out;

    dim3 grid((M_DIM / BM) * (N_DIM / BN));  // 1024 blocks
    dim3 block(512);
    linear_gl<<<grid, block, 0, stream>>>(x, w, b, out);
}

// Round 9
// 141.268 us; speedup vs baseline: 1.1002x; 1.1002x over previous
//
#include <hip/hip_runtime.h>
#include <hip/hip_bf16.h>

// Linear layer: out[M,N] = x[M,K] @ W[N,K]^T + b[N], fp32 in/out.
// M=32768, N=512, K=512. bf16 MFMA, fp32 accumulate.
// R5-R12 summary: every clean structure (4-wave reg-staged dbuf, 8-wave,
//   16 waves/CU, phase-split, gload_lds+vmcnt(4)) lands 53-66 us; best
//   53-56. Falsified: barrier vmcnt-drain (R9), occupancy (R11), coarse
//   deep-ILP (R10), gload_lds staging for f32 inputs (R12: read-side cvt
//   x6 amplification + wave-level bank conflicts). Absolute-time cross-
//   check: m102's verified m97-structure curve gives 53.7 us at our exact
//   FLOP size (2048^3-equiv) — we sit ON the documented plain-HIP curve.
// R13 (this): last untouched phase — the epilogue. Swap MFMA operands
//   (mfma(wF, aF, acc)): D transposes so each lane holds 4 CONSECUTIVE
//   N-cols of one M-row (mapping col=lane&15 -> M-row l16, row=kh*4+reg
//   -> N-col; shape-determined, dtype-independent). A/B operand lane
//   layouts are symmetric and aF/wF use identical addressing -> K-loop
//   unchanged. Epilogue: 16 aligned dwordx4 stores + 4 floatx4 bias
//   loads per thread (was 64 scattered dword stores). Each 64B line is
//   completed by 4 kh-lanes within one instruction -> WRITE stays ~66MB.
//   Gates: WRITE <= 75 MB, VGPR <= 128, conflicts 0, absmax <= 0.015625.

#define M_DIM 32768
#define N_DIM 512
#define K_DIM 512
#define BK 32
#define LDA 32   // bf16 elems per row (64 B); swizzled, no pad needed

typedef __bf16 bf16x8 __attribute__((ext_vector_type(8)));
typedef __bf16 bf16x4 __attribute__((ext_vector_type(4)));
typedef float floatx4 __attribute__((ext_vector_type(4)));

__global__ __launch_bounds__(256, 3) void linear_dbuf(
    const float* __restrict__ A,    // [M, K]
    const float* __restrict__ W,    // [N, K]
    const float* __restrict__ bias, // [N]
    float* __restrict__ C)          // [M, N]
{
    // 2 buffers x 2 arrays x 128 rows x 32 bf16 x 2 B = 32 KiB total.
    __shared__ __bf16 sA[2][128 * LDA];
    __shared__ __bf16 sW[2][128 * LDA];

    const int t = threadIdx.x;
    const int bid = blockIdx.x;
    // XCD swizzle: 4 n-tiles of an m-tile land on one XCD adjacent slots.
    const int nT = (bid >> 3) & 3;
    const int mT = (bid & 7) | ((bid >> 5) << 3);
    const int mBlock = mT * 128;
    const int nBlock = nT * 128;

    const int wave = t >> 6;
    const int lane = t & 63;
    const int mW = (wave >> 1) * 64;
    const int nW = (wave & 1) * 64;
    const int kh = lane >> 4;
    const int l16 = lane & 15;

    floatx4 acc[4][4];
#pragma unroll
    for (int i = 0; i < 4; ++i)
#pragma unroll
        for (int j = 0; j < 4; ++j)
            acc[i][j] = (floatx4)0.f;

    // Staging map: thread t covers rows sRow+{0,32,64,96}, 4 floats at col
    // sCol. Coalesced 128B per 8-lane row-group.
    const int sRow = t >> 3;
    const int sCol = (t & 7) * 4;
    // Swizzled elem offset within a row: each row = 4 chunks of 8 bf16 (16 B);
    // chunk' = chunk ^ ((row>>1)&3). (row>>1)&3 is invariant under row += 32,
    // so one constant serves all 4 staged rows. sCol&4 selects the 8 B half.
    const int wOff = (((sCol >> 3) ^ ((sRow >> 1) & 3)) << 3) + (sCol & 4);
    // Read side: fragment chunk kh of row (.. + l16); (row>>1)&3 == (l16>>1)&3
    // since mW, mi*16, nW, ni*16 are all multiples of 16.
    const int rk = (kh ^ ((l16 >> 1) & 3)) << 3;

    const float* aBase = A + (size_t)(mBlock + sRow) * K_DIM + sCol;
    const float* wBase = W + (size_t)(nBlock + sRow) * K_DIM + sCol;

    // Register prefetch: A has two sets (distance 2), W one set (distance 1).
    floatx4 pa[2][4], pw[4];
#pragma unroll
    for (int i = 0; i < 4; ++i) {
        pa[0][i] = *(const floatx4*)(aBase + (size_t)i * 32 * K_DIM);
        pa[1][i] = *(const floatx4*)(aBase + 32 + (size_t)i * 32 * K_DIM);
        pw[i]    = *(const floatx4*)(wBase + (size_t)i * 32 * K_DIM);
    }

#define STEP(cur, kt)                                                         \
    {                                                                         \
        _Pragma("unroll") for (int i = 0; i < 4; ++i) {                       \
            const int row = sRow + i * 32;                                    \
            bf16x4 ab, wb;                                                    \
            _Pragma("unroll") for (int j = 0; j < 4; ++j) {                   \
                ab[j] = (__bf16)pa[cur][i][j];                                \
                wb[j] = (__bf16)pw[i][j];                                     \
            }                                                                 \
            *(bf16x4*)&sA[cur][row * LDA + wOff] = ab;                        \
            *(bf16x4*)&sW[cur][row * LDA + wOff] = wb;                        \
        }                                                                     \
        /* T4 barrier (R9-verified): drain LDS (lgkm) only; global       */   \
        /* prefetch loads stay in flight across the barrier.             */   \
        asm volatile("s_waitcnt lgkmcnt(0)" ::: "memory");                    \
        __builtin_amdgcn_s_barrier();                                         \
        if ((kt) + BK < K_DIM) /* W for next iter: issue FIRST */             \
            _Pragma("unroll") for (int i = 0; i < 4; ++i)                     \
                pw[i] = *(const floatx4*)(wBase + (kt) + BK +                 \
                                          (size_t)i * 32 * K_DIM);            \
        if ((kt) + 2 * BK < K_DIM) /* A for iter+2 into the freed set */      \
            _Pragma("unroll") for (int i = 0; i < 4; ++i)                     \
                pa[cur][i] = *(const floatx4*)(aBase + (kt) + 2 * BK +        \
                                               (size_t)i * 32 * K_DIM);       \
        bf16x8 aF[4], wF[4];                                                  \
        _Pragma("unroll") for (int mi = 0; mi < 4; ++mi)                      \
            aF[mi] = *(const bf16x8*)&sA[cur][(mW + mi * 16 + l16) * LDA +    \
                                             rk];                             \
        _Pragma("unroll") for (int ni = 0; ni < 4; ++ni)                      \
            wF[ni] = *(const bf16x8*)&sW[cur][(nW + ni * 16 + l16) * LDA +    \
                                             rk];                             \
        /* SWAPPED operand order: D = W_slab * A_slab -> lane holds one  */   \
        /* M-row x 4 consecutive N-cols (coalesced dwordx4 C-store).     */   \
        _Pragma("unroll") for (int mi = 0; mi < 4; ++mi)                      \
            _Pragma("unroll") for (int ni = 0; ni < 4; ++ni)                  \
                acc[mi][ni] = __builtin_amdgcn_mfma_f32_16x16x32_bf16(        \
                    wF[ni], aF[mi], acc[mi][ni], 0, 0, 0);                    \
    }

    for (int it8 = 0; it8 < 8; ++it8) {
        const int kt = it8 * 2 * BK;
        STEP(0, kt);
        STEP(1, kt + BK);
    }
#undef STEP

    // Epilogue (swapped D mapping): M-row = l16, N-col = kh*4 + reg.
    // acc[mi][ni][j] = C[mBlock+mW+mi*16+l16][nBlock+nW+ni*16+kh*4+j].
    // One aligned dwordx4 store per (mi,ni); 4 kh-lanes complete each
    // 64B line within the same instruction.
#pragma unroll
    for (int mi = 0; mi < 4; ++mi) {
        const int grow = mBlock + mW + mi * 16 + l16;
#pragma unroll
        for (int ni = 0; ni < 4; ++ni) {
            const int gcol = nBlock + nW + ni * 16 + kh * 4;
            const floatx4 bv = *(const floatx4*)&bias[gcol];
            *(floatx4*)&C[(size_t)grow * N_DIM + gcol] = acc[mi][ni] + bv;
        }
    }
}

extern "C" void kernel_launch(void* const* d_in, const int* in_sizes, int n_in,
                              void* d_out, int out_size, void* d_ws, size_t ws_size,
                              hipStream_t stream) {
    const float* x = (const float*)d_in[0];
    const float* w = (const float*)d_in[1];
    const float* b = (const float*)d_in[2];
    float* out = (float*)d_out;

    dim3 grid((M_DIM / 128) * (N_DIM / 128));  // 1024 blocks, 1D for swizzle
    dim3 block(256);
    linear_dbuf<<<grid, block, 0, stream>>>(x, w, b, out);
}